// Round 17
// baseline (115.965 us; speedup 1.0000x reference)
//
#include <hip/hip_runtime.h>
#include <hip/hip_bf16.h>

// TripletLoss N=8192, D=128. Round 18: triangular (symmetric) pairs kernel.
// Ledger r8/r16/r17: 2-barrier 49.5us, big-dbuf 58.4, small-dbuf 55.0 --
// VALUBusy pinned ~39% in all three; scheduling changes exhausted. The
// untouched lever: d(i,j)=d(j,i). Upper-triangle tiles only (half the MFMA/
// LDS/staging/epilogue work): tile (a,jb>=a) yields row-sums for strip a
// (lane-reduce, as before) AND col-sums for strip jb (quad-reduce, 2 shfl).
// Load balance: pairing p = strips {p, 127-p} = 129 tiles constant; x32
// chunks = 2048 blocks. Diagonal tiles (jb==a) contain both orderings ->
// row-sums only, no double count. Col slices per wave in LDS (sCol[4][64],
// non-atomic), flushed (128 global atomics/tile) into acc[8192][2] during
// the NEXT tile's staging phase. Row flush per phase via atomics. acc is
// memset-zeroed; finalize = corr + acc (no jsplit loop).
// t-units: Fb,x2 pre-scaled by AK1=sqrt2*log2(e); C-init -(x2i+x2j)/2 =>
// acc = -AK1^2*d2/2; t=sqrt(-acc); exp(-dist)=exp2(-t); dist=t*ln2;
// positives exp(dist-30)=exp2(t+C2).

typedef __bf16 bf16x8 __attribute__((ext_vector_type(8)));
typedef float f32x4 __attribute__((ext_vector_type(4)));

#define NROWS 8192
#define DIM 128
#define LDS_STRIDE 136    // 128+8 bf16 pad: 272B rows (17x16B, odd -> b128 spread)
#define NLABELS 512
#define GCAP 64           // max rows/label (E=16; P(>64) ~ 1e-30)
#define NPAIR 64          // strip pairings (128 strips of 64 rows)
#define NCHUNK 32         // chunks per pairing -> 2048 blocks
#define MTILES 129        // tiles per strip-pair: (128-p) + (p+1)
#define MARGIN_F 0.3f
#define AK1F 2.04027892f      // sqrt2 * log2(e)
#define AK1SQ 4.16273807f     // AK1^2
#define EPS_T 2.08137e-8f     // AK1^2 * 5e-9 (matches reference clip(d2,1e-8))
#define C2F (-43.2808512f)    // -30*log2(e)
#define LN2F 0.69314718f

// ---------------- kernel 1: scaled bf16 cast + row norms + zero gstat ------
__global__ __launch_bounds__(256) void prep_kernel(const float* __restrict__ F,
                                                   __hip_bfloat16* __restrict__ Fb,
                                                   float* __restrict__ x2,
                                                   float* __restrict__ gstat) {
    const int tid = threadIdx.x;
    const int wave = tid >> 6, lane = tid & 63;
    const int row = blockIdx.x * 4 + wave;
    float2 f = ((const float2*)(F + (size_t)row * DIM))[lane];
    f.x *= AK1F; f.y *= AK1F;
    ((__hip_bfloat162*)(Fb + (size_t)row * DIM))[lane] = __float22bfloat162_rn(f);
    float ss = f.x * f.x + f.y * f.y;
#pragma unroll
    for (int m = 32; m > 0; m >>= 1) ss += __shfl_xor(ss, m, 64);
    if (lane == 0) x2[row] = ss;
    if (blockIdx.x == 0 && tid < 4) gstat[tid] = 0.f;
}

// ---------------- tile body: 16x16 MFMA + mining + optional col-sums -------
template<bool DIAG>
__device__ __forceinline__ void tile_body(const __hip_bfloat16* __restrict__ sB,
                                          const float* __restrict__ sX2h,
                                          const bf16x8 (&a)[4],
                                          const float (&x2ih)[4],
                                          float (&nl4)[4], float (&ns4)[4],
                                          float2* __restrict__ sColW,
                                          int lm, int quad, int ig0, int jbase) {
#pragma unroll
    for (int jt = 0; jt < 4; ++jt) {
        const int jl = jt * 16 + lm;
        const __hip_bfloat16* bp = sB + jl * LDS_STRIDE + quad * 8;
        const float xjh = sX2h[jl];
        f32x4 acc;
#pragma unroll
        for (int r = 0; r < 4; ++r) acc[r] = x2ih[r] + xjh;
#pragma unroll
        for (int kc = 0; kc < 4; ++kc) {
            bf16x8 b = *(const bf16x8*)(bp + kc * 32);
            acc = __builtin_amdgcn_mfma_f32_16x16x32_bf16(a[kc], b, acc, 0, 0, 0);
        }
        const int dj = jbase + jl - ig0;   // self-pair iff dj == r (diag only)
        float cl = 0.f, cs = 0.f;
#pragma unroll
        for (int r = 0; r < 4; ++r) {
            float d2h = fmaxf(-acc[r], EPS_T);          // = AK1^2*d2/2, clipped
            float t = __builtin_amdgcn_sqrtf(d2h);      // dist = t*ln2
            float ne = __builtin_amdgcn_exp2f(-t);      // exp(-dist)
            if (DIAG) ne = (dj == r) ? 0.f : ne;
            nl4[r] += ne;
            ns4[r] = fmaf(ne, t, ns4[r]);
            if (!DIAG) { cl += ne; cs = fmaf(ne, t, cs); }
        }
        if (!DIAG) {   // col-sums: reduce the 16 i-rows (over the 4 quads)
            cl += __shfl_xor(cl, 16, 64); cl += __shfl_xor(cl, 32, 64);
            cs += __shfl_xor(cs, 16, 64); cs += __shfl_xor(cs, 32, 64);
            if (quad == 0) sColW[jl] = make_float2(cl, cs);
        }
    }
}

// ---------------- kernel 2: triangular GEMM + mining; corr head on s<8 -----
__global__ __launch_bounds__(256, 3) void pairs_kernel(
        const __hip_bfloat16* __restrict__ Fb,
        const float* __restrict__ x2,
        const float* __restrict__ F,
        const int* __restrict__ labels,
        float* __restrict__ accg,       // [NROWS][2]: (nl, ns), memset-zeroed
        float4* __restrict__ corr) {
    __shared__ __hip_bfloat16 sB[64 * LDS_STRIDE];   // 17.4 KB
    __shared__ float sX2[64];                        // -0.5 * x2j
    __shared__ float2 sCol[4][64];                   // per-wave col slices
    __shared__ int sIdx[GCAP];
    __shared__ int sCnt;

    const int tid = threadIdx.x;
    const int p = blockIdx.x;       // pairing [0,64)
    const int s = blockIdx.y;       // chunk   [0,32)

    // ---- corr head: 512 blocks (s<8), one label each ----------------------
    if (s < 8) {
        const int L = s * 64 + p;
        if (tid == 0) sCnt = 0;
        __syncthreads();
        for (int it = 0; it < NROWS / 1024; ++it) {
            const int g = it * 1024 + tid * 4;
            int4 lv = *(const int4*)(labels + g);
#pragma unroll
            for (int k = 0; k < 4; ++k) {
                int lab = (k == 0) ? lv.x : (k == 1) ? lv.y : (k == 2) ? lv.z : lv.w;
                if (lab == L) {
                    int pos = atomicAdd(&sCnt, 1);
                    if (pos < GCAP) sIdx[pos] = g + k;
                }
            }
        }
        __syncthreads();
        const int gsz = sCnt < GCAP ? sCnt : GCAP;
        if (gsz > 0) {
            float* sAcc = (float*)sB;          // overlay, pre-staging
            float* plA = sAcc;
            float* psA = sAcc + GCAP;
            float* nlA = sAcc + 2 * GCAP;
            float* nsA = sAcc + 3 * GCAP;
            if (tid < GCAP) { plA[tid] = 0.f; psA[tid] = 0.f; nlA[tid] = 0.f; nsA[tid] = 0.f; }
            __syncthreads();
            const int npair = gsz * gsz;
            for (int pp = tid; pp < npair; pp += 256) {
                const int aI = pp / gsz, bI = pp - aI * gsz;
                if (aI == bI) continue;
                const float4* pa = (const float4*)(F + (size_t)sIdx[aI] * DIM);
                const float4* pb = (const float4*)(F + (size_t)sIdx[bI] * DIM);
                float dot = 0.f, ssa = 0.f, ssb = 0.f;
#pragma unroll 8
                for (int u = 0; u < 32; ++u) {
                    float4 va = pa[u], vb = pb[u];
                    dot = fmaf(va.x, vb.x, fmaf(va.y, vb.y, fmaf(va.z, vb.z, fmaf(va.w, vb.w, dot))));
                    ssa = fmaf(va.x, va.x, fmaf(va.y, va.y, fmaf(va.z, va.z, fmaf(va.w, va.w, ssa))));
                    ssb = fmaf(vb.x, vb.x, fmaf(vb.y, vb.y, fmaf(vb.z, vb.z, fmaf(vb.w, vb.w, ssb))));
                }
                float d2h = fmaxf((0.5f * (ssa + ssb) - dot) * AK1SQ, EPS_T);
                float t = __builtin_amdgcn_sqrtf(d2h);
                float ne = __builtin_amdgcn_exp2f(-t);
                float pe = __builtin_amdgcn_exp2f(t + C2F);
                unsafeAtomicAdd(&nlA[aI], ne);
                unsafeAtomicAdd(&nsA[aI], ne * t);
                unsafeAtomicAdd(&plA[aI], pe);
                unsafeAtomicAdd(&psA[aI], pe * t);
            }
            __syncthreads();
            if (tid < gsz)
                corr[sIdx[tid]] = make_float4(plA[tid], psA[tid], -nlA[tid], -nsA[tid]);
        }
        __syncthreads();   // corr LDS use done before staging overwrites
    }

    // ---- triangular main loop --------------------------------------------
    const int wave = tid >> 6;
    const int lane = tid & 63;
    const int quad = lane >> 4;
    const int lm = lane & 15;

    const int nA = 128 - p;                      // tiles in strip A (=p)
    const int tlo = (s * MTILES) >> 5;
    const int thi = ((s + 1) * MTILES) >> 5;     // chunk = [tlo, thi)

#pragma unroll 1
    for (int phase = 0; phase < 2; ++phase) {
        const int a = (phase == 0) ? p : 127 - p;         // strip index
        const int t0 = (phase == 0) ? tlo : (tlo > nA ? tlo : nA);
        const int t1 = (phase == 0) ? (thi < nA ? thi : nA) : thi;
        if (t0 >= t1) continue;                            // block-uniform

        const int rbase = a * 64 + wave * 16;
        bf16x8 afr[4];
#pragma unroll
        for (int kc = 0; kc < 4; ++kc)
            afr[kc] = *(const bf16x8*)(Fb + (size_t)(rbase + lm) * DIM + kc * 32 + quad * 8);
        const int ig0 = rbase + quad * 4;
        float x2ih[4];
#pragma unroll
        for (int r = 0; r < 4; ++r) x2ih[r] = -0.5f * x2[ig0 + r];
        float nl4[4] = {0,0,0,0}, ns4[4] = {0,0,0,0};

        int prevj = -1;   // jbase of pending col flush (-1: none)
        for (int t = t0; t < t1; ++t) {
            const int jb = (phase == 0) ? (p + t) : (127 - p) + (t - nA);
            const int jbase = jb << 6;
            __syncthreads();           // prev compute (incl. sCol writes) done
            if (prevj >= 0 && tid < 64) {   // flush prev tile's col-sums
                float2 c0 = sCol[0][tid], c1 = sCol[1][tid];
                float2 c2 = sCol[2][tid], c3 = sCol[3][tid];
                unsafeAtomicAdd(accg + (size_t)(prevj + tid) * 2,
                                c0.x + c1.x + c2.x + c3.x);
                unsafeAtomicAdd(accg + (size_t)(prevj + tid) * 2 + 1,
                                c0.y + c1.y + c2.y + c3.y);
            }
#pragma unroll
            for (int s2 = 0; s2 < 4; ++s2) {   // stage 64 x 256B
                int c = tid + s2 * 256;
                int jr = c >> 4, ck = c & 15;
                *(bf16x8*)(sB + jr * LDS_STRIDE + ck * 8) =
                    *(const bf16x8*)(Fb + (size_t)(jbase + jr) * DIM + ck * 8);
            }
            if (tid < 64) sX2[tid] = -0.5f * x2[jbase + tid];
            __syncthreads();

            if (jb == a) {    // diagonal: both orderings in-tile, rows only
                tile_body<true >(sB, sX2, afr, x2ih, nl4, ns4, sCol[wave],
                                 lm, quad, ig0, jbase);
                prevj = -1;
            } else {
                tile_body<false>(sB, sX2, afr, x2ih, nl4, ns4, sCol[wave],
                                 lm, quad, ig0, jbase);
                prevj = jbase;
            }
        }

        // row-sums for this strip: reduce over the 16 lm lanes, atomic-add
#pragma unroll
        for (int m = 1; m < 16; m <<= 1) {
#pragma unroll
            for (int r = 0; r < 4; ++r) {
                nl4[r] += __shfl_xor(nl4[r], m, 64);
                ns4[r] += __shfl_xor(ns4[r], m, 64);
            }
        }
        if (lm == 0) {
#pragma unroll
            for (int r = 0; r < 4; ++r) {
                unsafeAtomicAdd(accg + (size_t)(ig0 + r) * 2, nl4[r]);
                unsafeAtomicAdd(accg + (size_t)(ig0 + r) * 2 + 1, ns4[r]);
            }
        }
        __syncthreads();           // last tile's sCol writes done
        if (prevj >= 0 && tid < 64) {
            float2 c0 = sCol[0][tid], c1 = sCol[1][tid];
            float2 c2 = sCol[2][tid], c3 = sCol[3][tid];
            unsafeAtomicAdd(accg + (size_t)(prevj + tid) * 2,
                            c0.x + c1.x + c2.x + c3.x);
            unsafeAtomicAdd(accg + (size_t)(prevj + tid) * 2 + 1,
                            c0.y + c1.y + c2.y + c3.y);
        }
    }
}

// ---------------- kernel 3: per-row loss, reduce, final divide -------------
__global__ __launch_bounds__(256) void finalize_kernel(const float* __restrict__ accg,
                                                       const float4* __restrict__ corr,
                                                       float* __restrict__ gstat,
                                                       float* __restrict__ out) {
    const int row = blockIdx.x * 256 + threadIdx.x;
    float4 c = corr[row];
    float nl = c.z + accg[(size_t)row * 2];       // corr subtracts same-label mass
    float ns = c.w + accg[(size_t)row * 2 + 1];
    float sum = 0.f, cnt = 0.f;
    if (c.x > 0.f && nl > 0.f) {
        float x = fmaf(LN2F, c.y / c.x - ns / nl, MARGIN_F);   // wp - wn + margin
        sum = fmaxf(x, 0.f) + log1pf(__expf(-fabsf(x)));       // stable softplus
        cnt = 1.f;
    }
#pragma unroll
    for (int m = 32; m > 0; m >>= 1) {
        sum += __shfl_xor(sum, m, 64);
        cnt += __shfl_xor(cnt, m, 64);
    }
    __shared__ float sS[4], sC[4];
    const int wave = threadIdx.x >> 6, lane = threadIdx.x & 63;
    if (lane == 0) { sS[wave] = sum; sC[wave] = cnt; }
    __syncthreads();
    if (threadIdx.x == 0) {
        unsafeAtomicAdd(&gstat[0], sS[0] + sS[1] + sS[2] + sS[3]);
        unsafeAtomicAdd(&gstat[1], sC[0] + sC[1] + sC[2] + sC[3]);
        __threadfence();
        unsigned t = atomicAdd((unsigned*)(gstat + 2), 1u);
        if (t == (unsigned)(gridDim.x - 1)) {
            float s2 = unsafeAtomicAdd(&gstat[0], 0.f);   // L2 reads
            float c2 = unsafeAtomicAdd(&gstat[1], 0.f);
            out[0] = s2 / fmaxf(c2, 1.f);
        }
    }
}

extern "C" void kernel_launch(void* const* d_in, const int* in_sizes, int n_in,
                              void* d_out, int out_size, void* d_ws, size_t ws_size,
                              hipStream_t stream) {
    const float* F = (const float*)d_in[0];
    const int* labels = (const int*)d_in[1];
    float* out = (float*)d_out;

    char* ws = (char*)d_ws;
    __hip_bfloat16* Fb = (__hip_bfloat16*)ws;                        // 2 MB
    size_t off = (size_t)NROWS * DIM * 2;
    float* x2 = (float*)(ws + off);    off += (size_t)NROWS * 4;     // 32 KB
    float4* corr = (float4*)(ws + off); off += (size_t)NROWS * 16;   // 128 KB
    float* accg = (float*)(ws + off);  off += (size_t)NROWS * 8;     // 64 KB
    float* gstat = (float*)(ws + off);                               // 16 B

    hipMemsetAsync(accg, 0, (size_t)NROWS * 8, stream);
    prep_kernel<<<NROWS / 4, 256, 0, stream>>>(F, Fb, x2, gstat);
    pairs_kernel<<<dim3(NPAIR, NCHUNK), 256, 0, stream>>>(
        Fb, x2, F, labels, accg, corr);
    finalize_kernel<<<NROWS / 256, 256, 0, stream>>>(accg, corr, gstat, out);
}